// Round 9
// baseline (419.630 us; speedup 1.0000x reference)
//
#include <hip/hip_runtime.h>
#include <hip/hip_fp16.h>

#define N_ATOMS   50000
#define ATOM_FDIM 133
#define HIDDEN    128
#define DEPTH     3
#define N_EDGES   800000
#define N_MOLS    1024
#define BN_EPS    1e-5f
#define K_IN_PAD  160   // 133 padded to 5*32

typedef _Float16 f16x8 __attribute__((ext_vector_type(8)));
typedef _Float16 f16x2 __attribute__((ext_vector_type(2)));
typedef float    f32x4 __attribute__((ext_vector_type(4)));

struct __align__(8) half4pack { __half2 a, b; };

// ---------------- histogram ----------------
__global__ void hist_kernel(const int* __restrict__ idx, int n, int* __restrict__ cnt) {
    int i = blockIdx.x * blockDim.x + threadIdx.x;
    if (i < n) atomicAdd(&cnt[idx[i]], 1);
}

// ---------------- hierarchical exclusive scan ----------------
__global__ void scan_block_kernel(const int* __restrict__ in, int* __restrict__ out,
                                  int* __restrict__ bsum, int n) {
    __shared__ int buf[256];
    int i = blockIdx.x * 256 + threadIdx.x;
    int v = (i < n) ? in[i] : 0;
    buf[threadIdx.x] = v;
    __syncthreads();
    #pragma unroll
    for (int off = 1; off < 256; off <<= 1) {
        int t = (threadIdx.x >= off) ? buf[threadIdx.x - off] : 0;
        __syncthreads();
        buf[threadIdx.x] += t;
        __syncthreads();
    }
    if (i < n) out[i] = buf[threadIdx.x] - v;
    if (threadIdx.x == 255) bsum[blockIdx.x] = buf[255];
}

__global__ void scan_top_kernel(int* __restrict__ bsum, int nb) {
    __shared__ int buf[256];
    int v = (threadIdx.x < nb) ? bsum[threadIdx.x] : 0;
    buf[threadIdx.x] = v;
    __syncthreads();
    #pragma unroll
    for (int off = 1; off < 256; off <<= 1) {
        int t = (threadIdx.x >= off) ? buf[threadIdx.x - off] : 0;
        __syncthreads();
        buf[threadIdx.x] += t;
        __syncthreads();
    }
    if (threadIdx.x < nb) bsum[threadIdx.x] = buf[threadIdx.x] - v;
}

__global__ void scan_add_kernel(const int* __restrict__ partial, const int* __restrict__ bsum,
                                int* __restrict__ rowptr, int* __restrict__ wcur,
                                int n, int total) {
    int i = blockIdx.x * 256 + threadIdx.x;
    if (i < n) {
        int v = partial[i] + bsum[blockIdx.x];
        rowptr[i] = v;
        wcur[i]   = v;
    }
    if (i == 0) rowptr[n] = total;
}

// ---------------- FUSED: CSR fill (drain-bound) + setup (compute) in one grid ----------------
#define FB (N_EDGES / 256)   // 3125
__global__ void fill_setup_kernel(const int* __restrict__ src, const int* __restrict__ tgt,
                                  int* __restrict__ wcur, unsigned short* __restrict__ col,
                                  const float* __restrict__ f,
                                  const float* __restrict__ W_in,
                                  const float* __restrict__ W1,
                                  const float* __restrict__ W2,
                                  const int* __restrict__ seg,
                                  __half* __restrict__ Ah, __half* __restrict__ Wt,
                                  float* __restrict__ stats, int* __restrict__ moloff)
{
    if (blockIdx.x < FB) {
        int e = blockIdx.x * 256 + threadIdx.x;
        int t = tgt[e];
        int p = atomicAdd(&wcur[t], 1);
        col[p] = (unsigned short)src[e];
        return;
    }
    const int NCH = N_ATOMS * (K_IN_PAD / 4);
    const int NW4 = (128 * K_IN_PAD + 2 * DEPTH * 128 * 128) / 4;
    int i = (blockIdx.x - FB) * 256 + threadIdx.x;
    if (i < NCH) {
        int row = i / (K_IN_PAD / 4);
        int c4  = (i - row * (K_IN_PAD / 4)) * 4;
        float v[4];
        #pragma unroll
        for (int u = 0; u < 4; ++u) {
            int k = c4 + u;
            v[u] = (k < ATOM_FDIM) ? f[(size_t)row * ATOM_FDIM + k] : 0.f;
        }
        half4pack p;
        p.a = __float22half2_rn(make_float2(v[0], v[1]));
        p.b = __float22half2_rn(make_float2(v[2], v[3]));
        *(half4pack*)&Ah[(size_t)row * K_IN_PAD + c4] = p;
        return;
    }
    int j = i - NCH;
    if (j < NW4) {
        float v[4];
        #pragma unroll
        for (int u = 0; u < 4; ++u) {
            int e = j * 4 + u;
            if (e < 128 * K_IN_PAD) {
                int n = e / K_IN_PAD, k = e - n * K_IN_PAD;
                v[u] = (k < ATOM_FDIM) ? W_in[(size_t)k * 128 + n] : 0.f;
            } else if (e < 128 * K_IN_PAD + DEPTH * 128 * 128) {
                int q = e - 128 * K_IN_PAD;
                int d = q >> 14, r = q & 16383;
                int n = r >> 7, k = r & 127;
                v[u] = W1[((size_t)d * 128 + k) * 128 + n];
            } else {
                int q = e - 128 * K_IN_PAD - DEPTH * 128 * 128;
                int d = q >> 14, r = q & 16383;
                int n = r >> 7, k = r & 127;
                v[u] = W2[((size_t)d * 128 + k) * 128 + n];
            }
        }
        half4pack p;
        p.a = __float22half2_rn(make_float2(v[0], v[1]));
        p.b = __float22half2_rn(make_float2(v[2], v[3]));
        *(half4pack*)&Wt[j * 4] = p;
        return;
    }
    int m = j - NW4;
    if (m < DEPTH * 256) stats[m] = 0.f;
    if (m <= N_MOLS) {
        int lo = 0, hi = N_ATOMS;
        while (lo < hi) {
            int mid = (lo + hi) >> 1;
            if (seg[mid] < m) lo = mid + 1; else hi = mid;
        }
        moloff[m] = lo;
    }
}

#define LDS_S 40   // padded stride (halves) per 32-half k-chunk row

// ---------------- MFMA GEMM, K=160 fixed (input projection): single stage, ONE barrier ----
__global__ __launch_bounds__(256, 2) void mfma_gemm160(
    const __half* __restrict__ A, const __half* __restrict__ Bt,
    const float* __restrict__ bias, __half* __restrict__ C, int M)
{
    __shared__ __align__(16) __half As[5 * 128 * LDS_S];  // 50 KB
    __shared__ __align__(16) __half Bs[5 * 128 * LDS_S];  // 50 KB

    const int t = threadIdx.x;
    const int w = t >> 6, lane = t & 63;
    const int wm = w >> 1, wn = w & 1;
    const int l15 = lane & 15, quad = lane >> 4;
    const int row0 = blockIdx.x * 128;

    f32x4 acc[4][4];
    #pragma unroll
    for (int mt = 0; mt < 4; ++mt)
        #pragma unroll
        for (int nt = 0; nt < 4; ++nt) acc[mt][nt] = (f32x4){0.f, 0.f, 0.f, 0.f};

    #pragma unroll
    for (int i = 0; i < 10; ++i) {
        int c = i * 256 + t;
        int r = c / 20, o = c - r * 20;
        int kc = o >> 2, oo = o & 3;
        int row = row0 + r;
        uint4 v = make_uint4(0, 0, 0, 0);
        if (row < M) v = *(const uint4*)&A[(size_t)row * K_IN_PAD + o * 8];
        *(uint4*)&As[(kc * 128 + r) * LDS_S + oo * 8] = v;
    }
    #pragma unroll
    for (int i = 0; i < 10; ++i) {
        int c = i * 256 + t;
        int r = c / 20, o = c - r * 20;
        int kc = o >> 2, oo = o & 3;
        uint4 v = *(const uint4*)&Bt[(size_t)r * K_IN_PAD + o * 8];
        *(uint4*)&Bs[(kc * 128 + r) * LDS_S + oo * 8] = v;
    }
    __syncthreads();

    #pragma unroll
    for (int kc = 0; kc < 5; ++kc) {
        f16x8 af[4], bf[4];
        #pragma unroll
        for (int mt = 0; mt < 4; ++mt)
            af[mt] = *(const f16x8*)&As[(kc * 128 + wm * 64 + mt * 16 + l15) * LDS_S + quad * 8];
        #pragma unroll
        for (int nt = 0; nt < 4; ++nt)
            bf[nt] = *(const f16x8*)&Bs[(kc * 128 + wn * 64 + nt * 16 + l15) * LDS_S + quad * 8];
        #pragma unroll
        for (int mt = 0; mt < 4; ++mt)
            #pragma unroll
            for (int nt = 0; nt < 4; ++nt)
                acc[mt][nt] = __builtin_amdgcn_mfma_f32_16x16x32_f16(af[mt], bf[nt], acc[mt][nt], 0, 0, 0);
    }

    #pragma unroll
    for (int nt = 0; nt < 4; ++nt) {
        int col = wn * 64 + nt * 16 + l15;
        float b = bias[col];
        #pragma unroll
        for (int mt = 0; mt < 4; ++mt) {
            #pragma unroll
            for (int r = 0; r < 4; ++r) {
                int row = row0 + wm * 64 + mt * 16 + quad * 4 + r;
                if (row < M) {
                    float o = fmaxf(acc[mt][nt][r] + b, 0.f);   // ReLU
                    C[(size_t)row * 128 + col] = __float2half(o);
                }
            }
        }
    }
}

// ---------------- FUSED MLP: hpre = relu(agg@W1+b1)@W2+b2, + BN stats ----------------
__global__ __launch_bounds__(256, 2) void mlp_fused(
    const __half* __restrict__ A, const __half* __restrict__ B1t,
    const __half* __restrict__ B2t,
    const float* __restrict__ bias1, const float* __restrict__ bias2,
    __half* __restrict__ C, int M,
    float* __restrict__ s1, float* __restrict__ s2)
{
    __shared__ __align__(16) __half As[4 * 128 * LDS_S];  // 40 KB
    __shared__ __align__(16) __half Bs[4 * 128 * LDS_S];  // 40 KB

    const int t = threadIdx.x;
    const int w = t >> 6, lane = t & 63;
    const int wm = w >> 1, wn = w & 1;
    const int l15 = lane & 15, quad = lane >> 4;
    const int row0 = blockIdx.x * 128;

    f32x4 acc[4][4];
    #pragma unroll
    for (int mt = 0; mt < 4; ++mt)
        #pragma unroll
        for (int nt = 0; nt < 4; ++nt) acc[mt][nt] = (f32x4){0.f, 0.f, 0.f, 0.f};

    #pragma unroll
    for (int i = 0; i < 8; ++i) {
        int c = i * 256 + t;
        int r = c >> 4, o = c & 15;
        int kc = o >> 2, oo = o & 3;
        int row = row0 + r;
        uint4 v = make_uint4(0, 0, 0, 0);
        if (row < M) v = *(const uint4*)&A[(size_t)row * 128 + o * 8];
        *(uint4*)&As[(kc * 128 + r) * LDS_S + oo * 8] = v;
    }
    #pragma unroll
    for (int i = 0; i < 8; ++i) {
        int c = i * 256 + t;
        int r = c >> 4, o = c & 15;
        int kc = o >> 2, oo = o & 3;
        uint4 v = *(const uint4*)&B1t[(size_t)r * 128 + o * 8];
        *(uint4*)&Bs[(kc * 128 + r) * LDS_S + oo * 8] = v;
    }
    __syncthreads();

    #pragma unroll
    for (int kc = 0; kc < 4; ++kc) {
        f16x8 af[4], bf[4];
        #pragma unroll
        for (int mt = 0; mt < 4; ++mt)
            af[mt] = *(const f16x8*)&As[(kc * 128 + wm * 64 + mt * 16 + l15) * LDS_S + quad * 8];
        #pragma unroll
        for (int nt = 0; nt < 4; ++nt)
            bf[nt] = *(const f16x8*)&Bs[(kc * 128 + wn * 64 + nt * 16 + l15) * LDS_S + quad * 8];
        #pragma unroll
        for (int mt = 0; mt < 4; ++mt)
            #pragma unroll
            for (int nt = 0; nt < 4; ++nt)
                acc[mt][nt] = __builtin_amdgcn_mfma_f32_16x16x32_f16(af[mt], bf[nt], acc[mt][nt], 0, 0, 0);
    }
    __syncthreads();

    #pragma unroll
    for (int nt = 0; nt < 4; ++nt) {
        int k = wn * 64 + nt * 16 + l15;
        float b = bias1[k];
        int kc = k >> 5, ko = k & 31;
        #pragma unroll
        for (int mt = 0; mt < 4; ++mt) {
            #pragma unroll
            for (int r = 0; r < 4; ++r) {
                int rl = wm * 64 + mt * 16 + quad * 4 + r;
                float h = fmaxf(acc[mt][nt][r] + b, 0.f);
                As[(kc * 128 + rl) * LDS_S + ko] = __float2half(h);
            }
        }
    }
    #pragma unroll
    for (int i = 0; i < 8; ++i) {
        int c = i * 256 + t;
        int r = c >> 4, o = c & 15;
        int kc = o >> 2, oo = o & 3;
        uint4 v = *(const uint4*)&B2t[(size_t)r * 128 + o * 8];
        *(uint4*)&Bs[(kc * 128 + r) * LDS_S + oo * 8] = v;
    }
    __syncthreads();

    #pragma unroll
    for (int mt = 0; mt < 4; ++mt)
        #pragma unroll
        for (int nt = 0; nt < 4; ++nt) acc[mt][nt] = (f32x4){0.f, 0.f, 0.f, 0.f};
    #pragma unroll
    for (int kc = 0; kc < 4; ++kc) {
        f16x8 af[4], bf[4];
        #pragma unroll
        for (int mt = 0; mt < 4; ++mt)
            af[mt] = *(const f16x8*)&As[(kc * 128 + wm * 64 + mt * 16 + l15) * LDS_S + quad * 8];
        #pragma unroll
        for (int nt = 0; nt < 4; ++nt)
            bf[nt] = *(const f16x8*)&Bs[(kc * 128 + wn * 64 + nt * 16 + l15) * LDS_S + quad * 8];
        #pragma unroll
        for (int mt = 0; mt < 4; ++mt)
            #pragma unroll
            for (int nt = 0; nt < 4; ++nt)
                acc[mt][nt] = __builtin_amdgcn_mfma_f32_16x16x32_f16(af[mt], bf[nt], acc[mt][nt], 0, 0, 0);
    }

    float ps[4] = {0, 0, 0, 0}, pss[4] = {0, 0, 0, 0};
    #pragma unroll
    for (int nt = 0; nt < 4; ++nt) {
        int col = wn * 64 + nt * 16 + l15;
        float b = bias2[col];
        #pragma unroll
        for (int mt = 0; mt < 4; ++mt) {
            #pragma unroll
            for (int r = 0; r < 4; ++r) {
                int row = row0 + wm * 64 + mt * 16 + quad * 4 + r;
                if (row < M) {
                    float o = acc[mt][nt][r] + b;
                    ps[nt] += o;
                    pss[nt] += o * o;
                    C[(size_t)row * 128 + col] = __float2half(o);
                }
            }
        }
    }

    float* red1 = (float*)As;
    float* red2 = (float*)Bs;
    int contrib = wm * 4 + quad;
    __syncthreads();
    #pragma unroll
    for (int nt = 0; nt < 4; ++nt) {
        int col = wn * 64 + nt * 16 + l15;
        red1[contrib * 128 + col] = ps[nt];
        red2[contrib * 128 + col] = pss[nt];
    }
    __syncthreads();
    if (t < 128) {
        float s = 0.f, q = 0.f;
        #pragma unroll
        for (int g = 0; g < 8; ++g) {
            s += red1[g * 128 + t];
            q += red2[g * 128 + t];
        }
        atomicAdd(&s1[t], s);
        atomicAdd(&s2[t], q);
    }
}

// ---------------- aggregate (wave-per-atom), fp16 tree-sum chunks ----------------
// BN=true: relu(sc*h+sh) = sc*relu(h + c), c = sh/sc (gamma==1 -> sc>0).
// Per-edge: v_pk_add_f16 + v_pk_max_f16; sc applied once per 8-edge chunk.
template<bool BN>
__global__ __launch_bounds__(256) void aggregate_kernel(
    const f16x2* __restrict__ xh2, const int* __restrict__ rowptr,
    const unsigned short* __restrict__ col, const float* __restrict__ eps_param, int d,
    const float* __restrict__ s1, const float* __restrict__ s2,
    const float* __restrict__ gamma, const float* __restrict__ beta, int dprev,
    f16x2* __restrict__ aggh2)
{
    int gw = (blockIdx.x * 256 + threadIdx.x) >> 6;   // one wave per atom
    int lane = threadIdx.x & 63;
    float e1 = 1.0f + eps_param[d];

    float sc_x = 1.f, sc_y = 1.f, c_x = 0.f, c_y = 0.f;
    f16x2 c2 = (f16x2){(_Float16)0.f, (_Float16)0.f};
    if (BN) {
        const float inv_n = 1.0f / (float)N_ATOMS;
        int c0 = lane * 2;
        float m0 = s1[c0] * inv_n;
        float v0 = fmaxf(s2[c0] * inv_n - m0 * m0, 0.f);
        float m1 = s1[c0 + 1] * inv_n;
        float v1 = fmaxf(s2[c0 + 1] * inv_n - m1 * m1, 0.f);
        sc_x = gamma[dprev * 128 + c0]     * rsqrtf(v0 + BN_EPS);
        sc_y = gamma[dprev * 128 + c0 + 1] * rsqrtf(v1 + BN_EPS);
        c_x = beta[dprev * 128 + c0]     / sc_x - m0;
        c_y = beta[dprev * 128 + c0 + 1] / sc_y - m1;
        c2 = (f16x2){(_Float16)c_x, (_Float16)c_y};
    }

    // self term (fp32)
    f16x2 ah = xh2[(size_t)gw * 64 + lane];
    float2 a = make_float2((float)ah.x, (float)ah.y);
    if (BN) {
        a.x = sc_x * fmaxf(a.x + c_x, 0.f);
        a.y = sc_y * fmaxf(a.y + c_y, 0.f);
    }
    float2 acc;
    acc.x = a.x * e1;
    acc.y = a.y * e1;

    const f16x2 z2 = (f16x2){(_Float16)0.f, (_Float16)0.f};
    int s = rowptr[gw], e = rowptr[gw + 1];
    int i = s;
    for (; i + 8 <= e; i += 8) {
        f16x2 v[8];
        #pragma unroll
        for (int u = 0; u < 8; ++u) {
            int c = col[i + u];
            v[u] = xh2[(size_t)c * 64 + lane];
        }
        if (BN) {
            #pragma unroll
            for (int u = 0; u < 8; ++u)
                v[u] = __builtin_elementwise_max(v[u] + c2, z2);
        }
        f16x2 p0 = v[0] + v[1], p1 = v[2] + v[3];
        f16x2 p2 = v[4] + v[5], p3 = v[6] + v[7];
        f16x2 q0 = p0 + p1, q1 = p2 + p3;
        f16x2 r2 = q0 + q1;
        float frx = (float)r2.x, fry = (float)r2.y;
        if (BN) {
            acc.x = fmaf(sc_x, frx, acc.x);
            acc.y = fmaf(sc_y, fry, acc.y);
        } else {
            acc.x += frx;
            acc.y += fry;
        }
    }
    for (; i < e; ++i) {
        f16x2 vh = xh2[(size_t)col[i] * 64 + lane];
        float fx = (float)vh.x, fy = (float)vh.y;
        if (BN) {
            fx = sc_x * fmaxf(fx + c_x, 0.f);
            fy = sc_y * fmaxf(fy + c_y, 0.f);
        }
        acc.x += fx;
        acc.y += fy;
    }
    aggh2[(size_t)gw * 64 + lane] = (f16x2){(_Float16)acc.x, (_Float16)acc.y};
}

// ---------------- per-molecule mean pooling with fused BN+ReLU ----------------
__global__ void pool_kernel(const __half* __restrict__ hh, const int* __restrict__ off,
                            const float* __restrict__ s1, const float* __restrict__ s2,
                            const float* __restrict__ gamma, const float* __restrict__ beta,
                            int dprev, float* __restrict__ out)
{
    int m = blockIdx.x;
    int c = threadIdx.x;
    const float inv_n = 1.0f / (float)N_ATOMS;
    float mean = s1[c] * inv_n;
    float var = fmaxf(s2[c] * inv_n - mean * mean, 0.f);
    float sc = gamma[dprev * 128 + c] * rsqrtf(var + BN_EPS);
    float sh = beta[dprev * 128 + c] - mean * sc;
    int s = off[m], e = off[m + 1];
    float acc = 0.f;
    for (int r = s; r < e; ++r) {
        float v = __half2float(hh[(size_t)r * 128 + c]);
        acc += fmaxf(v * sc + sh, 0.f);
    }
    int cnt = e - s;
    out[m * 128 + c] = (cnt > 0) ? acc / (float)cnt : 0.f;
}

// ---------------- launcher ----------------
extern "C" void kernel_launch(void* const* d_in, const int* in_sizes, int n_in,
                              void* d_out, int out_size, void* d_ws, size_t ws_size,
                              hipStream_t stream)
{
    const float* f_atoms   = (const float*)d_in[0];
    const float* W_in      = (const float*)d_in[1];
    const float* b_in      = (const float*)d_in[2];
    const float* W1        = (const float*)d_in[3];
    const float* b1        = (const float*)d_in[4];
    const float* W2        = (const float*)d_in[5];
    const float* b2        = (const float*)d_in[6];
    const float* gamma     = (const float*)d_in[7];
    const float* beta      = (const float*)d_in[8];
    const float* eps_param = (const float*)d_in[9];
    const int*   edge_index= (const int*)d_in[10];
    const int*   seg       = (const int*)d_in[11];
    const int*   src = edge_index;
    const int*   tgt = edge_index + N_EDGES;
    float* out = (float*)d_out;

    char* ws = (char*)d_ws;
    size_t off = 0;
    auto alloc = [&](size_t bytes) -> char* {
        char* p = ws + off;
        off += (bytes + 255) & ~(size_t)255;
        return p;
    };
    __half* xh    = (__half*)alloc((size_t)N_ATOMS * HIDDEN * 2);   // x0 = relu(proj)
    __half* aggh  = (__half*)alloc((size_t)N_ATOMS * HIDDEN * 2);   // aggregate out
    __half* hpre  = (__half*)alloc((size_t)N_ATOMS * HIDDEN * 2);   // mlp out (pre-BN h)
    __half* Ah    = (__half*)alloc((size_t)N_ATOMS * K_IN_PAD * 2);
    __half* Wt    = (__half*)alloc((size_t)(128 * K_IN_PAD + 2 * DEPTH * 128 * 128) * 2);
    int*   rowptr = (int*)alloc((N_ATOMS + 1) * 4);
    int*   wcur   = (int*)alloc(N_ATOMS * 4);
    int*   partial= (int*)alloc(N_ATOMS * 4);
    int*   bsum   = (int*)alloc(256 * 4);
    unsigned short* col = (unsigned short*)alloc((size_t)N_EDGES * 2);
    float* s12    = (float*)alloc(DEPTH * 256 * 4);
    int*   moloff = (int*)alloc((N_MOLS + 1) * 4);

    const __half* Wt_in = Wt;
    const __half* W1t   = Wt + 128 * K_IN_PAD;
    const __half* W2t   = W1t + DEPTH * 128 * 128;

    // ---- CSR count + scan ----
    hipMemsetAsync(wcur, 0, N_ATOMS * 4, stream);
    hist_kernel<<<(N_EDGES + 255) / 256, 256, 0, stream>>>(tgt, N_EDGES, wcur);
    const int NB = (N_ATOMS + 255) / 256;   // 196
    scan_block_kernel<<<NB, 256, 0, stream>>>(wcur, partial, bsum, N_ATOMS);
    scan_top_kernel<<<1, 256, 0, stream>>>(bsum, NB);
    scan_add_kernel<<<NB, 256, 0, stream>>>(partial, bsum, rowptr, wcur, N_ATOMS, N_EDGES);

    // ---- fused CSR fill + setup (overlap drain with conversion) ----
    {
        const int NCH = N_ATOMS * (K_IN_PAD / 4);
        const int NW4 = (128 * K_IN_PAD + 2 * DEPTH * 128 * 128) / 4;
        const int SB  = (NCH + NW4 + N_MOLS + 1 + 255) / 256;
        fill_setup_kernel<<<FB + SB, 256, 0, stream>>>(
            src, tgt, wcur, col, f_atoms, W_in, W1, W2, seg, Ah, Wt, s12, moloff);
    }

    // ---- input projection + ReLU -> fp16 x0 ----
    const int GB = (N_ATOMS + 127) / 128;   // 391
    mfma_gemm160<<<GB, 256, 0, stream>>>(Ah, Wt_in, b_in, xh, N_ATOMS);

    for (int d = 0; d < DEPTH; ++d) {
        float* s1d = s12 + d * 256;
        float* s2d = s1d + 128;
        if (d == 0) {
            aggregate_kernel<false><<<N_ATOMS / 4, 256, 0, stream>>>(
                (const f16x2*)xh, rowptr, col, eps_param, d,
                nullptr, nullptr, nullptr, nullptr, 0, (f16x2*)aggh);
        } else {
            float* s1p = s12 + (d - 1) * 256;
            float* s2p = s1p + 128;
            aggregate_kernel<true><<<N_ATOMS / 4, 256, 0, stream>>>(
                (const f16x2*)hpre, rowptr, col, eps_param, d,
                s1p, s2p, gamma, beta, d - 1, (f16x2*)aggh);
        }
        mlp_fused<<<GB, 256, 0, stream>>>(
            aggh, W1t + (size_t)d * 128 * 128, W2t + (size_t)d * 128 * 128,
            b1 + d * HIDDEN, b2 + d * HIDDEN, hpre, N_ATOMS, s1d, s2d);
    }

    pool_kernel<<<N_MOLS, 128, 0, stream>>>(
        hpre, moloff, s12 + (DEPTH - 1) * 256, s12 + (DEPTH - 1) * 256 + 128,
        gamma, beta, DEPTH - 1, out);
}

// Round 10
// 391.946 us; speedup vs baseline: 1.0706x; 1.0706x over previous
//
#include <hip/hip_runtime.h>
#include <hip/hip_fp16.h>

#define N_ATOMS   50000
#define ATOM_FDIM 133
#define HIDDEN    128
#define DEPTH     3
#define N_EDGES   800000
#define N_MOLS    1024
#define BN_EPS    1e-5f
#define K_IN_PAD  160   // 133 padded to 5*32

typedef _Float16 f16x8 __attribute__((ext_vector_type(8)));
typedef _Float16 f16x2 __attribute__((ext_vector_type(2)));
typedef float    f32x4 __attribute__((ext_vector_type(4)));

struct __align__(8) half4pack { __half2 a, b; };

// ---------------- histogram ----------------
__global__ void hist_kernel(const int* __restrict__ idx, int n, int* __restrict__ cnt) {
    int i = blockIdx.x * blockDim.x + threadIdx.x;
    if (i < n) atomicAdd(&cnt[idx[i]], 1);
}

// ---------------- hierarchical exclusive scan ----------------
__global__ void scan_block_kernel(const int* __restrict__ in, int* __restrict__ out,
                                  int* __restrict__ bsum, int n) {
    __shared__ int buf[256];
    int i = blockIdx.x * 256 + threadIdx.x;
    int v = (i < n) ? in[i] : 0;
    buf[threadIdx.x] = v;
    __syncthreads();
    #pragma unroll
    for (int off = 1; off < 256; off <<= 1) {
        int t = (threadIdx.x >= off) ? buf[threadIdx.x - off] : 0;
        __syncthreads();
        buf[threadIdx.x] += t;
        __syncthreads();
    }
    if (i < n) out[i] = buf[threadIdx.x] - v;
    if (threadIdx.x == 255) bsum[blockIdx.x] = buf[255];
}

__global__ void scan_top_kernel(int* __restrict__ bsum, int nb) {
    __shared__ int buf[256];
    int v = (threadIdx.x < nb) ? bsum[threadIdx.x] : 0;
    buf[threadIdx.x] = v;
    __syncthreads();
    #pragma unroll
    for (int off = 1; off < 256; off <<= 1) {
        int t = (threadIdx.x >= off) ? buf[threadIdx.x - off] : 0;
        __syncthreads();
        buf[threadIdx.x] += t;
        __syncthreads();
    }
    if (threadIdx.x < nb) bsum[threadIdx.x] = buf[threadIdx.x] - v;
}

__global__ void scan_add_kernel(const int* __restrict__ partial, const int* __restrict__ bsum,
                                int* __restrict__ rowptr, int* __restrict__ wcur,
                                int n, int total) {
    int i = blockIdx.x * 256 + threadIdx.x;
    if (i < n) {
        int v = partial[i] + bsum[blockIdx.x];
        rowptr[i] = v;
        wcur[i]   = v;
    }
    if (i == 0) rowptr[n] = total;
}

// ---------------- FUSED: CSR fill + setup in one grid (neutral but saves a launch) ----------
#define FB (N_EDGES / 256)   // 3125
__global__ void fill_setup_kernel(const int* __restrict__ src, const int* __restrict__ tgt,
                                  int* __restrict__ wcur, unsigned short* __restrict__ col,
                                  const float* __restrict__ f,
                                  const float* __restrict__ W_in,
                                  const float* __restrict__ W1,
                                  const float* __restrict__ W2,
                                  const int* __restrict__ seg,
                                  __half* __restrict__ Ah, __half* __restrict__ Wt,
                                  float* __restrict__ stats, int* __restrict__ moloff)
{
    if (blockIdx.x < FB) {
        int e = blockIdx.x * 256 + threadIdx.x;
        int t = tgt[e];
        int p = atomicAdd(&wcur[t], 1);
        col[p] = (unsigned short)src[e];
        return;
    }
    const int NCH = N_ATOMS * (K_IN_PAD / 4);
    const int NW4 = (128 * K_IN_PAD + 2 * DEPTH * 128 * 128) / 4;
    int i = (blockIdx.x - FB) * 256 + threadIdx.x;
    if (i < NCH) {
        int row = i / (K_IN_PAD / 4);
        int c4  = (i - row * (K_IN_PAD / 4)) * 4;
        float v[4];
        #pragma unroll
        for (int u = 0; u < 4; ++u) {
            int k = c4 + u;
            v[u] = (k < ATOM_FDIM) ? f[(size_t)row * ATOM_FDIM + k] : 0.f;
        }
        half4pack p;
        p.a = __float22half2_rn(make_float2(v[0], v[1]));
        p.b = __float22half2_rn(make_float2(v[2], v[3]));
        *(half4pack*)&Ah[(size_t)row * K_IN_PAD + c4] = p;
        return;
    }
    int j = i - NCH;
    if (j < NW4) {
        float v[4];
        #pragma unroll
        for (int u = 0; u < 4; ++u) {
            int e = j * 4 + u;
            if (e < 128 * K_IN_PAD) {
                int n = e / K_IN_PAD, k = e - n * K_IN_PAD;
                v[u] = (k < ATOM_FDIM) ? W_in[(size_t)k * 128 + n] : 0.f;
            } else if (e < 128 * K_IN_PAD + DEPTH * 128 * 128) {
                int q = e - 128 * K_IN_PAD;
                int d = q >> 14, r = q & 16383;
                int n = r >> 7, k = r & 127;
                v[u] = W1[((size_t)d * 128 + k) * 128 + n];
            } else {
                int q = e - 128 * K_IN_PAD - DEPTH * 128 * 128;
                int d = q >> 14, r = q & 16383;
                int n = r >> 7, k = r & 127;
                v[u] = W2[((size_t)d * 128 + k) * 128 + n];
            }
        }
        half4pack p;
        p.a = __float22half2_rn(make_float2(v[0], v[1]));
        p.b = __float22half2_rn(make_float2(v[2], v[3]));
        *(half4pack*)&Wt[j * 4] = p;
        return;
    }
    int m = j - NW4;
    if (m < DEPTH * 256) stats[m] = 0.f;
    if (m <= N_MOLS) {
        int lo = 0, hi = N_ATOMS;
        while (lo < hi) {
            int mid = (lo + hi) >> 1;
            if (seg[mid] < m) lo = mid + 1; else hi = mid;
        }
        moloff[m] = lo;
    }
}

#define LDS_S 40   // padded stride (halves) per 32-half k-chunk row

// ---------------- MFMA GEMM, K variable (input projection), K-loop, 20 KB LDS ----------------
template<bool RELU>
__global__ __launch_bounds__(256, 2) void mfma_gemm(
    const __half* __restrict__ A, const __half* __restrict__ Bt,
    const float* __restrict__ bias, __half* __restrict__ C, int M, int K)
{
    __shared__ __align__(16) __half As[128 * LDS_S];
    __shared__ __align__(16) __half Bs[128 * LDS_S];

    const int t = threadIdx.x;
    const int w = t >> 6, lane = t & 63;
    const int wm = w >> 1, wn = w & 1;
    const int l15 = lane & 15, quad = lane >> 4;
    const int row0 = blockIdx.x * 128;

    f32x4 acc[4][4];
    #pragma unroll
    for (int mt = 0; mt < 4; ++mt)
        #pragma unroll
        for (int nt = 0; nt < 4; ++nt) acc[mt][nt] = (f32x4){0.f, 0.f, 0.f, 0.f};

    for (int k0 = 0; k0 < K; k0 += 32) {
        #pragma unroll
        for (int i = 0; i < 2; ++i) {
            int c = t * 2 + i;
            int r = c >> 2, o = c & 3;
            int row = row0 + r;
            uint4 v = make_uint4(0, 0, 0, 0);
            if (row < M) v = *(const uint4*)&A[(size_t)row * K + k0 + o * 8];
            *(uint4*)&As[r * LDS_S + o * 8] = v;
        }
        #pragma unroll
        for (int i = 0; i < 2; ++i) {
            int c = t * 2 + i;
            int r = c >> 2, o = c & 3;
            uint4 v = *(const uint4*)&Bt[(size_t)r * K + k0 + o * 8];
            *(uint4*)&Bs[r * LDS_S + o * 8] = v;
        }
        __syncthreads();
        f16x8 af[4], bf[4];
        #pragma unroll
        for (int mt = 0; mt < 4; ++mt)
            af[mt] = *(const f16x8*)&As[(wm * 64 + mt * 16 + l15) * LDS_S + quad * 8];
        #pragma unroll
        for (int nt = 0; nt < 4; ++nt)
            bf[nt] = *(const f16x8*)&Bs[(wn * 64 + nt * 16 + l15) * LDS_S + quad * 8];
        #pragma unroll
        for (int mt = 0; mt < 4; ++mt)
            #pragma unroll
            for (int nt = 0; nt < 4; ++nt)
                acc[mt][nt] = __builtin_amdgcn_mfma_f32_16x16x32_f16(af[mt], bf[nt], acc[mt][nt], 0, 0, 0);
        __syncthreads();
    }

    #pragma unroll
    for (int nt = 0; nt < 4; ++nt) {
        int col = wn * 64 + nt * 16 + l15;
        float b = bias[col];
        #pragma unroll
        for (int mt = 0; mt < 4; ++mt) {
            #pragma unroll
            for (int r = 0; r < 4; ++r) {
                int row = row0 + wm * 64 + mt * 16 + quad * 4 + r;
                if (row < M) {
                    float o = acc[mt][nt][r] + b;
                    if (RELU) o = fmaxf(o, 0.f);
                    C[(size_t)row * 128 + col] = __float2half(o);
                }
            }
        }
    }
}

// ---------------- FUSED MLP: hpre = relu(agg@W1+b1)@W2+b2, + BN stats ----------------
__global__ __launch_bounds__(256, 2) void mlp_fused(
    const __half* __restrict__ A, const __half* __restrict__ B1t,
    const __half* __restrict__ B2t,
    const float* __restrict__ bias1, const float* __restrict__ bias2,
    __half* __restrict__ C, int M,
    float* __restrict__ s1, float* __restrict__ s2)
{
    __shared__ __align__(16) __half As[4 * 128 * LDS_S];  // 40 KB
    __shared__ __align__(16) __half Bs[4 * 128 * LDS_S];  // 40 KB

    const int t = threadIdx.x;
    const int w = t >> 6, lane = t & 63;
    const int wm = w >> 1, wn = w & 1;
    const int l15 = lane & 15, quad = lane >> 4;
    const int row0 = blockIdx.x * 128;

    f32x4 acc[4][4];
    #pragma unroll
    for (int mt = 0; mt < 4; ++mt)
        #pragma unroll
        for (int nt = 0; nt < 4; ++nt) acc[mt][nt] = (f32x4){0.f, 0.f, 0.f, 0.f};

    #pragma unroll
    for (int i = 0; i < 8; ++i) {
        int c = i * 256 + t;
        int r = c >> 4, o = c & 15;
        int kc = o >> 2, oo = o & 3;
        int row = row0 + r;
        uint4 v = make_uint4(0, 0, 0, 0);
        if (row < M) v = *(const uint4*)&A[(size_t)row * 128 + o * 8];
        *(uint4*)&As[(kc * 128 + r) * LDS_S + oo * 8] = v;
    }
    #pragma unroll
    for (int i = 0; i < 8; ++i) {
        int c = i * 256 + t;
        int r = c >> 4, o = c & 15;
        int kc = o >> 2, oo = o & 3;
        uint4 v = *(const uint4*)&B1t[(size_t)r * 128 + o * 8];
        *(uint4*)&Bs[(kc * 128 + r) * LDS_S + oo * 8] = v;
    }
    __syncthreads();

    #pragma unroll
    for (int kc = 0; kc < 4; ++kc) {
        f16x8 af[4], bf[4];
        #pragma unroll
        for (int mt = 0; mt < 4; ++mt)
            af[mt] = *(const f16x8*)&As[(kc * 128 + wm * 64 + mt * 16 + l15) * LDS_S + quad * 8];
        #pragma unroll
        for (int nt = 0; nt < 4; ++nt)
            bf[nt] = *(const f16x8*)&Bs[(kc * 128 + wn * 64 + nt * 16 + l15) * LDS_S + quad * 8];
        #pragma unroll
        for (int mt = 0; mt < 4; ++mt)
            #pragma unroll
            for (int nt = 0; nt < 4; ++nt)
                acc[mt][nt] = __builtin_amdgcn_mfma_f32_16x16x32_f16(af[mt], bf[nt], acc[mt][nt], 0, 0, 0);
    }
    __syncthreads();

    #pragma unroll
    for (int nt = 0; nt < 4; ++nt) {
        int k = wn * 64 + nt * 16 + l15;
        float b = bias1[k];
        int kc = k >> 5, ko = k & 31;
        #pragma unroll
        for (int mt = 0; mt < 4; ++mt) {
            #pragma unroll
            for (int r = 0; r < 4; ++r) {
                int rl = wm * 64 + mt * 16 + quad * 4 + r;
                float h = fmaxf(acc[mt][nt][r] + b, 0.f);
                As[(kc * 128 + rl) * LDS_S + ko] = __float2half(h);
            }
        }
    }
    #pragma unroll
    for (int i = 0; i < 8; ++i) {
        int c = i * 256 + t;
        int r = c >> 4, o = c & 15;
        int kc = o >> 2, oo = o & 3;
        uint4 v = *(const uint4*)&B2t[(size_t)r * 128 + o * 8];
        *(uint4*)&Bs[(kc * 128 + r) * LDS_S + oo * 8] = v;
    }
    __syncthreads();

    #pragma unroll
    for (int mt = 0; mt < 4; ++mt)
        #pragma unroll
        for (int nt = 0; nt < 4; ++nt) acc[mt][nt] = (f32x4){0.f, 0.f, 0.f, 0.f};
    #pragma unroll
    for (int kc = 0; kc < 4; ++kc) {
        f16x8 af[4], bf[4];
        #pragma unroll
        for (int mt = 0; mt < 4; ++mt)
            af[mt] = *(const f16x8*)&As[(kc * 128 + wm * 64 + mt * 16 + l15) * LDS_S + quad * 8];
        #pragma unroll
        for (int nt = 0; nt < 4; ++nt)
            bf[nt] = *(const f16x8*)&Bs[(kc * 128 + wn * 64 + nt * 16 + l15) * LDS_S + quad * 8];
        #pragma unroll
        for (int mt = 0; mt < 4; ++mt)
            #pragma unroll
            for (int nt = 0; nt < 4; ++nt)
                acc[mt][nt] = __builtin_amdgcn_mfma_f32_16x16x32_f16(af[mt], bf[nt], acc[mt][nt], 0, 0, 0);
    }

    float ps[4] = {0, 0, 0, 0}, pss[4] = {0, 0, 0, 0};
    #pragma unroll
    for (int nt = 0; nt < 4; ++nt) {
        int col = wn * 64 + nt * 16 + l15;
        float b = bias2[col];
        #pragma unroll
        for (int mt = 0; mt < 4; ++mt) {
            #pragma unroll
            for (int r = 0; r < 4; ++r) {
                int row = row0 + wm * 64 + mt * 16 + quad * 4 + r;
                if (row < M) {
                    float o = acc[mt][nt][r] + b;
                    ps[nt] += o;
                    pss[nt] += o * o;
                    C[(size_t)row * 128 + col] = __float2half(o);
                }
            }
        }
    }

    float* red1 = (float*)As;
    float* red2 = (float*)Bs;
    int contrib = wm * 4 + quad;
    __syncthreads();
    #pragma unroll
    for (int nt = 0; nt < 4; ++nt) {
        int col = wn * 64 + nt * 16 + l15;
        red1[contrib * 128 + col] = ps[nt];
        red2[contrib * 128 + col] = pss[nt];
    }
    __syncthreads();
    if (t < 128) {
        float s = 0.f, q = 0.f;
        #pragma unroll
        for (int g = 0; g < 8; ++g) {
            s += red1[g * 128 + t];
            q += red2[g * 128 + t];
        }
        atomicAdd(&s1[t], s);
        atomicAdd(&s2[t], q);
    }
}

// ---------------- aggregate: fp16-tree full chunks + clamped vectorized fp32 tail ----------
// BN=true: relu(sc*h+sh) = sc*relu(h + c), c = sh/sc (gamma==1 -> sc>0).
template<bool BN>
__global__ __launch_bounds__(256) void aggregate_kernel(
    const f16x2* __restrict__ xh2, const int* __restrict__ rowptr,
    const unsigned short* __restrict__ col, const float* __restrict__ eps_param, int d,
    const float* __restrict__ s1, const float* __restrict__ s2,
    const float* __restrict__ gamma, const float* __restrict__ beta, int dprev,
    f16x2* __restrict__ aggh2)
{
    int gw = (blockIdx.x * 256 + threadIdx.x) >> 6;   // one wave per atom
    int lane = threadIdx.x & 63;
    float e1 = 1.0f + eps_param[d];

    float sc_x = 1.f, sc_y = 1.f, c_x = 0.f, c_y = 0.f;
    f16x2 c2 = (f16x2){(_Float16)0.f, (_Float16)0.f};
    if (BN) {
        const float inv_n = 1.0f / (float)N_ATOMS;
        int c0 = lane * 2;
        float m0 = s1[c0] * inv_n;
        float v0 = fmaxf(s2[c0] * inv_n - m0 * m0, 0.f);
        float m1 = s1[c0 + 1] * inv_n;
        float v1 = fmaxf(s2[c0 + 1] * inv_n - m1 * m1, 0.f);
        sc_x = gamma[dprev * 128 + c0]     * rsqrtf(v0 + BN_EPS);
        sc_y = gamma[dprev * 128 + c0 + 1] * rsqrtf(v1 + BN_EPS);
        c_x = beta[dprev * 128 + c0]     / sc_x - m0;
        c_y = beta[dprev * 128 + c0 + 1] / sc_y - m1;
        c2 = (f16x2){(_Float16)c_x, (_Float16)c_y};
    }

    // self term (fp32)
    f16x2 ah = xh2[(size_t)gw * 64 + lane];
    float2 a = make_float2((float)ah.x, (float)ah.y);
    if (BN) {
        a.x = sc_x * fmaxf(a.x + c_x, 0.f);
        a.y = sc_y * fmaxf(a.y + c_y, 0.f);
    }
    float2 acc;
    acc.x = a.x * e1;
    acc.y = a.y * e1;

    const f16x2 z2 = (f16x2){(_Float16)0.f, (_Float16)0.f};
    int s = rowptr[gw], e = rowptr[gw + 1];
    int i = s;
    // fast path: full 8-edge chunks, packed fp16 tree reduce
    for (; i + 8 <= e; i += 8) {
        f16x2 v[8];
        #pragma unroll
        for (int u = 0; u < 8; ++u) {
            int c = col[i + u];
            v[u] = xh2[(size_t)c * 64 + lane];
        }
        if (BN) {
            #pragma unroll
            for (int u = 0; u < 8; ++u)
                v[u] = __builtin_elementwise_max(v[u] + c2, z2);
        }
        f16x2 p0 = v[0] + v[1], p1 = v[2] + v[3];
        f16x2 p2 = v[4] + v[5], p3 = v[6] + v[7];
        f16x2 r2 = (p0 + p1) + (p2 + p3);
        float frx = (float)r2.x, fry = (float)r2.y;
        if (BN) {
            acc.x = fmaf(sc_x, frx, acc.x);
            acc.y = fmaf(sc_y, fry, acc.y);
        } else {
            acc.x += frx;
            acc.y += fry;
        }
    }
    // tail: ONE clamped vectorized chunk, predicated fp32 accumulation
    if (i < e) {
        f16x2 v[8];
        #pragma unroll
        for (int u = 0; u < 8; ++u) {
            int idx = min(i + u, e - 1);
            int c = col[idx];
            v[u] = xh2[(size_t)c * 64 + lane];
        }
        #pragma unroll
        for (int u = 0; u < 8; ++u) {
            float fx = (float)v[u].x, fy = (float)v[u].y;
            if (BN) {
                fx = sc_x * fmaxf(fx + c_x, 0.f);
                fy = sc_y * fmaxf(fy + c_y, 0.f);
            }
            if (i + u < e) {
                acc.x += fx;
                acc.y += fy;
            }
        }
    }
    aggh2[(size_t)gw * 64 + lane] = (f16x2){(_Float16)acc.x, (_Float16)acc.y};
}

// ---------------- per-molecule mean pooling with fused BN+ReLU ----------------
__global__ void pool_kernel(const __half* __restrict__ hh, const int* __restrict__ off,
                            const float* __restrict__ s1, const float* __restrict__ s2,
                            const float* __restrict__ gamma, const float* __restrict__ beta,
                            int dprev, float* __restrict__ out)
{
    int m = blockIdx.x;
    int c = threadIdx.x;
    const float inv_n = 1.0f / (float)N_ATOMS;
    float mean = s1[c] * inv_n;
    float var = fmaxf(s2[c] * inv_n - mean * mean, 0.f);
    float sc = gamma[dprev * 128 + c] * rsqrtf(var + BN_EPS);
    float sh = beta[dprev * 128 + c] - mean * sc;
    int s = off[m], e = off[m + 1];
    float acc = 0.f;
    for (int r = s; r < e; ++r) {
        float v = __half2float(hh[(size_t)r * 128 + c]);
        acc += fmaxf(v * sc + sh, 0.f);
    }
    int cnt = e - s;
    out[m * 128 + c] = (cnt > 0) ? acc / (float)cnt : 0.f;
}

// ---------------- launcher ----------------
extern "C" void kernel_launch(void* const* d_in, const int* in_sizes, int n_in,
                              void* d_out, int out_size, void* d_ws, size_t ws_size,
                              hipStream_t stream)
{
    const float* f_atoms   = (const float*)d_in[0];
    const float* W_in      = (const float*)d_in[1];
    const float* b_in      = (const float*)d_in[2];
    const float* W1        = (const float*)d_in[3];
    const float* b1        = (const float*)d_in[4];
    const float* W2        = (const float*)d_in[5];
    const float* b2        = (const float*)d_in[6];
    const float* gamma     = (const float*)d_in[7];
    const float* beta      = (const float*)d_in[8];
    const float* eps_param = (const float*)d_in[9];
    const int*   edge_index= (const int*)d_in[10];
    const int*   seg       = (const int*)d_in[11];
    const int*   src = edge_index;
    const int*   tgt = edge_index + N_EDGES;
    float* out = (float*)d_out;

    char* ws = (char*)d_ws;
    size_t off = 0;
    auto alloc = [&](size_t bytes) -> char* {
        char* p = ws + off;
        off += (bytes + 255) & ~(size_t)255;
        return p;
    };
    __half* xh    = (__half*)alloc((size_t)N_ATOMS * HIDDEN * 2);   // x0 = relu(proj)
    __half* aggh  = (__half*)alloc((size_t)N_ATOMS * HIDDEN * 2);   // aggregate out
    __half* hpre  = (__half*)alloc((size_t)N_ATOMS * HIDDEN * 2);   // mlp out (pre-BN h)
    __half* Ah    = (__half*)alloc((size_t)N_ATOMS * K_IN_PAD * 2);
    __half* Wt    = (__half*)alloc((size_t)(128 * K_IN_PAD + 2 * DEPTH * 128 * 128) * 2);
    int*   rowptr = (int*)alloc((N_ATOMS + 1) * 4);
    int*   wcur   = (int*)alloc(N_ATOMS * 4);
    int*   partial= (int*)alloc(N_ATOMS * 4);
    int*   bsum   = (int*)alloc(256 * 4);
    unsigned short* col = (unsigned short*)alloc((size_t)N_EDGES * 2);
    float* s12    = (float*)alloc(DEPTH * 256 * 4);
    int*   moloff = (int*)alloc((N_MOLS + 1) * 4);

    const __half* Wt_in = Wt;
    const __half* W1t   = Wt + 128 * K_IN_PAD;
    const __half* W2t   = W1t + DEPTH * 128 * 128;

    // ---- CSR count + scan ----
    hipMemsetAsync(wcur, 0, N_ATOMS * 4, stream);
    hist_kernel<<<(N_EDGES + 255) / 256, 256, 0, stream>>>(tgt, N_EDGES, wcur);
    const int NB = (N_ATOMS + 255) / 256;   // 196
    scan_block_kernel<<<NB, 256, 0, stream>>>(wcur, partial, bsum, N_ATOMS);
    scan_top_kernel<<<1, 256, 0, stream>>>(bsum, NB);
    scan_add_kernel<<<NB, 256, 0, stream>>>(partial, bsum, rowptr, wcur, N_ATOMS, N_EDGES);

    // ---- fused CSR fill + setup ----
    {
        const int NCH = N_ATOMS * (K_IN_PAD / 4);
        const int NW4 = (128 * K_IN_PAD + 2 * DEPTH * 128 * 128) / 4;
        const int SB  = (NCH + NW4 + N_MOLS + 1 + 255) / 256;
        fill_setup_kernel<<<FB + SB, 256, 0, stream>>>(
            src, tgt, wcur, col, f_atoms, W_in, W1, W2, seg, Ah, Wt, s12, moloff);
    }

    // ---- input projection + ReLU -> fp16 x0 (K-loop GEMM, high occupancy) ----
    const int GB = (N_ATOMS + 127) / 128;   // 391
    mfma_gemm<true><<<GB, 256, 0, stream>>>(Ah, Wt_in, b_in, xh, N_ATOMS, K_IN_PAD);

    for (int d = 0; d < DEPTH; ++d) {
        float* s1d = s12 + d * 256;
        float* s2d = s1d + 128;
        if (d == 0) {
            aggregate_kernel<false><<<N_ATOMS / 4, 256, 0, stream>>>(
                (const f16x2*)xh, rowptr, col, eps_param, d,
                nullptr, nullptr, nullptr, nullptr, 0, (f16x2*)aggh);
        } else {
            float* s1p = s12 + (d - 1) * 256;
            float* s2p = s1p + 128;
            aggregate_kernel<true><<<N_ATOMS / 4, 256, 0, stream>>>(
                (const f16x2*)hpre, rowptr, col, eps_param, d,
                s1p, s2p, gamma, beta, d - 1, (f16x2*)aggh);
        }
        mlp_fused<<<GB, 256, 0, stream>>>(
            aggh, W1t + (size_t)d * 128 * 128, W2t + (size_t)d * 128 * 128,
            b1 + d * HIDDEN, b2 + d * HIDDEN, hpre, N_ATOMS, s1d, s2d);
    }

    pool_kernel<<<N_MOLS, 128, 0, stream>>>(
        hpre, moloff, s12 + (DEPTH - 1) * 256, s12 + (DEPTH - 1) * 256 + 128,
        gamma, beta, DEPTH - 1, out);
}